// Round 5
// baseline (359.574 us; speedup 1.0000x reference)
//
#include <hip/hip_runtime.h>
#include <stdint.h>

// Conv2d 3x3 SAME stride-1. x:(32,64,112,112) f32 NCHW, w:(64,64,3,3) OIHW.
// v5: f16 split-precision (hi+lo) MFMA implicit conv.
//   out = sum_c,tap [ (xhi+xlo)(whi+wlo) ] via 3 MFMA products (hh, hl, lh);
//   dropped lo*lo term ~2^-22 relative -> fp32-equivalent accuracy.
// Pass1: x -> xt planes, layout [n][h][cchunk=2][w][32c] f16.
// Pass2: w -> [tap][k][c] hi/lo f16 planes.
// Pass3: MFMA conv. v5 vs v4: block = 4 output rows, wave = 1 row x 64 kout
//   (4 B-frags per A-read -> half the LDS read traffic; 6-row staging,
//   halo amplification 1.5x). Staging still global_load_lds DMA, linear LDS.

#define N_ 32
#define C_ 64
#define H_ 112
#define W_ 112
#define K_ 64

typedef _Float16 f16;
typedef _Float16 f16x8 __attribute__((ext_vector_type(8)));
typedef float f32x4 __attribute__((ext_vector_type(4)));

typedef __attribute__((address_space(1))) const uint32_t g_u32;
typedef __attribute__((address_space(3))) uint32_t l_u32;

static constexpr size_t XT_E = (size_t)N_ * H_ * W_ * C_;  // f16 elems per plane
static constexpr size_t WT_E = (size_t)9 * K_ * C_;
static constexpr size_t WS_NEED = (2 * XT_E + 2 * WT_E) * 2;  // bytes

__device__ inline uint32_t split_pack(float v) {
    f16 h = (f16)v;
    f16 l = (f16)(v - (float)h);
    return (uint32_t)__builtin_bit_cast(uint16_t, h) |
           ((uint32_t)__builtin_bit_cast(uint16_t, l) << 16);
}

// ---------------- Pass 1: x (NCHW f32) -> xt_hi/xt_lo [n][h][cs][w][32] -----
__global__ __launch_bounds__(256)
void xform_x(const float* __restrict__ x, uint32_t* __restrict__ xt_hi,
             uint32_t* __restrict__ xt_lo) {
    __shared__ uint32_t lds[W_ * 67];   // [w][c] packed (hi|lo<<16), pad 67
    const int tid = threadIdx.x;
    const int n = blockIdx.x / H_;
    const int h = blockIdx.x % H_;

#pragma unroll
    for (int k = 0; k < 7; ++k) {
        int q = tid + k * 256;
        int c = q / 28;
        int wq = (q % 28) * 4;
        const float4 v = *reinterpret_cast<const float4*>(
            &x[((n * C_ + c) * H_ + h) * W_ + wq]);
        lds[(wq + 0) * 67 + c] = split_pack(v.x);
        lds[(wq + 1) * 67 + c] = split_pack(v.y);
        lds[(wq + 2) * 67 + c] = split_pack(v.z);
        lds[(wq + 3) * 67 + c] = split_pack(v.w);
    }
    __syncthreads();
#pragma unroll
    for (int k = 0; k < 14; ++k) {
        int m = tid + k * 256;
        int w = m >> 5;
        int cp = m & 31;
        uint32_t a = lds[w * 67 + 2 * cp];
        uint32_t b = lds[w * 67 + 2 * cp + 1];
        uint32_t hiw = (a & 0xffffu) | (b << 16);
        uint32_t low = (a >> 16) | (b & 0xffff0000u);
        int o = (((n * H_ + h) * 2 + (cp >> 4)) * W_ + w) * 16 + (cp & 15);
        xt_hi[o] = hiw;
        xt_lo[o] = low;
    }
}

// ---------------- Pass 2: w (OIHW f32) -> wt_hi/wt_lo [tap][k][c] f16 -------
__global__ __launch_bounds__(256)
void xform_w(const float* __restrict__ wgt, uint16_t* __restrict__ wt_hi,
             uint16_t* __restrict__ wt_lo) {
    int e = blockIdx.x * 256 + threadIdx.x;   // grid 144 -> e < 36864
    int t = e >> 12;
    int rem = e & 4095;
    int k = rem >> 6;
    int c = rem & 63;
    float v = wgt[(k * C_ + c) * 9 + t];
    f16 h = (f16)v;
    f16 l = (f16)(v - (float)h);
    wt_hi[e] = __builtin_bit_cast(uint16_t, h);
    wt_lo[e] = __builtin_bit_cast(uint16_t, l);
}

// ---------------- Pass 3: MFMA conv ----------------------------------------
// Block: (n, hq) -> output rows h0=4*hq .. h0+3. 256 thr = 4 waves.
// Wave wv = output row mr. Wave tile: 112 pix x 64 kout (nf = 0..3).
// LDS: 6 input rows x 114 pix x 64B (one plane, one 32c chunk), linear.
__global__ __launch_bounds__(256, 2)
void conv_mfma(const f16* __restrict__ xt_hi, const f16* __restrict__ xt_lo,
               const f16* __restrict__ wt_hi, const f16* __restrict__ wt_lo,
               float* __restrict__ out) {
    __shared__ alignas(16) char xs[6 * 114 * 64];   // 43,776 B

    const int tid = threadIdx.x;
    const int lane = tid & 63;
    const int wv = tid >> 6;
    const int mr = wv;            // output row within block
    const int l15 = lane & 15;
    const int l4 = lane >> 4;

    const int bid = blockIdx.x;
    const int n = bid / 28;
    const int h0 = (bid % 28) * 4;

    // ---- one-time halo zero: cols p=0,113 for all 6 rows; OOB rows fully
    {
        const f16x8 z = {};
        if (tid < 48) {           // 6 rows x 2 cols x 4 chunks
            int r = tid / 8, pc = (tid >> 2) & 1, ch = tid & 3;
            int p = pc ? 113 : 0;
            *reinterpret_cast<f16x8*>(&xs[(r * 114 + p) * 64 + ch * 16]) = z;
        }
        if (h0 == 0)              // row r=0 (ih=-1)
            for (int q = tid; q < 114 * 4; q += 256)
                *reinterpret_cast<f16x8*>(&xs[(q >> 2) * 64 + (q & 3) * 16]) = z;
        if (h0 == H_ - 4)         // row r=5 (ih=112)
            for (int q = tid; q < 114 * 4; q += 256)
                *reinterpret_cast<f16x8*>(&xs[(5 * 114 + (q >> 2)) * 64 + (q & 3) * 16]) = z;
    }

    f32x4 acc[7][4];
#pragma unroll
    for (int f = 0; f < 7; ++f)
#pragma unroll
        for (int g = 0; g < 4; ++g) {
            f32x4 zz = {0.f, 0.f, 0.f, 0.f};
            acc[f][g] = zz;
        }

#pragma unroll
    for (int pp = 0; pp < 2; ++pp) {
        const f16* xp = pp ? xt_lo : xt_hi;
#pragma unroll
        for (int cs = 0; cs < 2; ++cs) {
            __syncthreads();   // previous phase done reading xs
            // stage 6 rows: wave wv -> rows wv, wv+4 (waves 2,3: one row)
            for (int rr = wv; rr < 6; rr += 4) {
                const int ih = h0 - 1 + rr;
                if ((unsigned)ih < (unsigned)H_) {
                    const char* gsrc = (const char*)xp +
                        (size_t)(((n * H_ + ih) * 2 + cs) * W_) * 64;
                    char* ldst = &xs[(rr * 114 + 1) * 64];
#pragma unroll
                    for (int i = 0; i < 7; ++i)
                        __builtin_amdgcn_global_load_lds(
                            (g_u32*)(gsrc + i * 1024 + lane * 16),
                            (l_u32*)(ldst + i * 1024), 16, 0, 0);
                }
            }
            __syncthreads();   // staging visible

            const int c0 = cs * 32;
#pragma unroll
            for (int tap = 0; tap < 9; ++tap) {
                const int r = tap / 3;
                const int s = tap % 3;
                // B frags: lane holds wt[tap][kout = nf*16 + l15][c0 + l4*8..+7]
                const int wo = (tap * K_ + l15) * C_ + c0 + l4 * 8;
                f16x8 Bh[4], Bl[4];
#pragma unroll
                for (int nf = 0; nf < 4; ++nf) {
                    Bh[nf] = *reinterpret_cast<const f16x8*>(&wt_hi[wo + nf * 16 * C_]);
                    if (pp == 0)
                        Bl[nf] = *reinterpret_cast<const f16x8*>(&wt_lo[wo + nf * 16 * C_]);
                }
#pragma unroll
                for (int f = 0; f < 7; ++f) {
                    const f16x8 A = *reinterpret_cast<const f16x8*>(
                        &xs[((mr + r) * 114 + f * 16 + l15 + s) * 64 + l4 * 16]);
#pragma unroll
                    for (int nf = 0; nf < 4; ++nf) {
                        acc[f][nf] = __builtin_amdgcn_mfma_f32_16x16x32_f16(
                            A, Bh[nf], acc[f][nf], 0, 0, 0);
                        if (pp == 0)
                            acc[f][nf] = __builtin_amdgcn_mfma_f32_16x16x32_f16(
                                A, Bl[nf], acc[f][nf], 0, 0, 0);
                    }
                }
            }
        }
    }

    // epilogue: D row = pixel (f*16 + l4*4 + reg), col = kout (nf*16 + l15)
    const int h = h0 + mr;
#pragma unroll
    for (int f = 0; f < 7; ++f)
#pragma unroll
        for (int nf = 0; nf < 4; ++nf) {
            const int k = nf * 16 + l15;
            const int w = f * 16 + l4 * 4;
            *reinterpret_cast<f32x4*>(&out[((n * K_ + k) * H_ + h) * W_ + w]) =
                acc[f][nf];
        }
}

// ---------------- Fallback: fp32 direct (v1) -------------------------------
constexpr int CB = 8;
constexpr int WP = 114;
__global__ __launch_bounds__(256, 4)
void conv3x3_fp32_v1(const float* __restrict__ x, const float* __restrict__ wgt,
                     float* __restrict__ out) {
    __shared__ float xsf[CB][3][WP];
    __shared__ float wsf[CB][9][K_];
    const int tid = threadIdx.x;
    const int tw = tid & 15, tk = tid >> 4;
    const int w0 = tw * 7, k0 = tk * 4;
    const int h = blockIdx.x % H_;
    const int n = blockIdx.x / H_;
    float acc[4][7];
#pragma unroll
    for (int a = 0; a < 4; ++a)
#pragma unroll
        for (int b = 0; b < 7; ++b) acc[a][b] = 0.f;
    for (int c0 = 0; c0 < C_; c0 += CB) {
        __syncthreads();
        for (int idx = tid; idx < CB * 3 * WP; idx += 256) {
            int cc = idx / (3 * WP);
            int rem = idx - cc * (3 * WP);
            int r = rem / WP, j = rem - r * WP;
            int ih = h - 1 + r, iw = j - 1;
            float v = 0.f;
            if ((unsigned)ih < (unsigned)H_ && (unsigned)iw < (unsigned)W_)
                v = x[((n * C_ + c0 + cc) * H_ + ih) * W_ + iw];
            xsf[cc][r][j] = v;
        }
        for (int idx = tid; idx < CB * 9 * K_; idx += 256) {
            int k = idx & 63, t = idx >> 6;
            int p = t % 9, cc = t / 9;
            wsf[cc][p][k] = wgt[(k * C_ + cc + c0) * 9 + p];
        }
        __syncthreads();
#pragma unroll
        for (int cc = 0; cc < CB; ++cc)
#pragma unroll
            for (int kh = 0; kh < 3; ++kh) {
                float xv[9];
#pragma unroll
                for (int i = 0; i < 9; ++i) xv[i] = xsf[cc][kh][w0 + i];
#pragma unroll
                for (int kw = 0; kw < 3; ++kw) {
                    const float4 wv = *reinterpret_cast<const float4*>(&wsf[cc][kh * 3 + kw][k0]);
                    const float wvv[4] = {wv.x, wv.y, wv.z, wv.w};
#pragma unroll
                    for (int kk = 0; kk < 4; ++kk)
#pragma unroll
                        for (int wi = 0; wi < 7; ++wi)
                            acc[kk][wi] = fmaf(wvv[kk], xv[wi + kw], acc[kk][wi]);
                }
            }
    }
#pragma unroll
    for (int kk = 0; kk < 4; ++kk) {
        float* op = &out[((n * K_ + k0 + kk) * H_ + h) * W_ + w0];
#pragma unroll
        for (int wi = 0; wi < 7; ++wi) op[wi] = acc[kk][wi];
    }
}

extern "C" void kernel_launch(void* const* d_in, const int* in_sizes, int n_in,
                              void* d_out, int out_size, void* d_ws, size_t ws_size,
                              hipStream_t stream) {
    const float* x = (const float*)d_in[0];
    const float* wgt = (const float*)d_in[1];
    float* out = (float*)d_out;

    if (ws_size < WS_NEED) {
        hipLaunchKernelGGL(conv3x3_fp32_v1, dim3(N_ * H_), dim3(256), 0, stream,
                           x, wgt, out);
        return;
    }

    char* ws = (char*)d_ws;
    f16* xt_hi = (f16*)ws;
    f16* xt_lo = xt_hi + XT_E;
    f16* wt_hi = xt_lo + XT_E;
    f16* wt_lo = wt_hi + WT_E;

    hipLaunchKernelGGL(xform_x, dim3(N_ * H_), dim3(256), 0, stream,
                       x, (uint32_t*)xt_hi, (uint32_t*)xt_lo);
    hipLaunchKernelGGL(xform_w, dim3((int)(WT_E / 256)), dim3(256), 0, stream,
                       wgt, (uint16_t*)wt_hi, (uint16_t*)wt_lo);
    hipLaunchKernelGGL(conv_mfma, dim3(N_ * 28), dim3(256), 0, stream,
                       xt_hi, xt_lo, wt_hi, wt_lo, out);
}

// Round 8
// 338.087 us; speedup vs baseline: 1.0636x; 1.0636x over previous
//
#include <hip/hip_runtime.h>
#include <stdint.h>

// Conv2d 3x3 SAME stride-1. x:(32,64,112,112) f32 NCHW, w:(64,64,3,3) OIHW.
// v8 = v7 (never benched: acquisition timeout) + XCD-chunked block swizzle.
// f16 split-precision (hi+lo) MFMA implicit conv:
//   out = sum_c,tap [ (xhi+xlo)(whi+wlo) ] via 3 MFMA products (hh, hl, lh).
// vs v5 (201us, MfmaUtil 17.6%, 3.6M bank conflicts, WRITE 220MB=2.13x):
//   - XOR-swizzled A-tile LDS: slot' = ch ^ ((pix>>1)&3); pre-swizzled global
//     src for global_load_lds (LDS dest linear), read offsets fold to sOff[s].
//   - balanced DMA staging: 42 (row,chunk) units round-robined over 4 waves.
//   - xform_x: uint4 stores (was 56 scalar stores/thread).
//   - LDS-restaged epilogue -> 448B-contiguous out writes (amp 2.13->~1).
//   - NEW (v8): XCD-chunked blockIdx swizzle (grid 896 = 8*112, bijective).

#define N_ 32
#define C_ 64
#define H_ 112
#define W_ 112
#define K_ 64

typedef _Float16 f16;
typedef _Float16 f16x8 __attribute__((ext_vector_type(8)));
typedef float f32x4 __attribute__((ext_vector_type(4)));

typedef __attribute__((address_space(1))) const uint32_t g_u32;
typedef __attribute__((address_space(3))) uint32_t l_u32;

static constexpr size_t XT_E = (size_t)N_ * H_ * W_ * C_;  // f16 elems per plane
static constexpr size_t WT_E = (size_t)9 * K_ * C_;
static constexpr size_t WS_NEED = (2 * XT_E + 2 * WT_E) * 2;  // bytes

__device__ inline uint32_t split_pack(float v) {
    f16 h = (f16)v;
    f16 l = (f16)(v - (float)h);
    return (uint32_t)__builtin_bit_cast(uint16_t, h) |
           ((uint32_t)__builtin_bit_cast(uint16_t, l) << 16);
}

// ---------------- Pass 1: x (NCHW f32) -> xt_hi/xt_lo [n][h][cs][w][32] -----
__global__ __launch_bounds__(256)
void xform_x(const float* __restrict__ x, uint32_t* __restrict__ xt_hi,
             uint32_t* __restrict__ xt_lo) {
    __shared__ uint32_t lds[W_ * 67];   // [w][c] packed (hi|lo<<16), pad 67
    const int tid = threadIdx.x;
    const int n = blockIdx.x / H_;
    const int h = blockIdx.x % H_;

#pragma unroll
    for (int k = 0; k < 7; ++k) {
        int q = tid + k * 256;
        int c = q / 28;
        int wq = (q % 28) * 4;
        const float4 v = *reinterpret_cast<const float4*>(
            &x[((n * C_ + c) * H_ + h) * W_ + wq]);
        lds[(wq + 0) * 67 + c] = split_pack(v.x);
        lds[(wq + 1) * 67 + c] = split_pack(v.y);
        lds[(wq + 2) * 67 + c] = split_pack(v.z);
        lds[(wq + 3) * 67 + c] = split_pack(v.w);
    }
    __syncthreads();
    // store phase: 1792 uint4 units (u<896: hi plane, else lo), wave-uniform arr
#pragma unroll
    for (int k = 0; k < 7; ++k) {
        int u = tid + k * 256;          // 0..1791
        int arr = (u >= 896) ? 1 : 0;
        int v = arr ? (u - 896) : u;    // 0..895
        int w = v >> 3;
        int cp4 = v & 7;                // group of 4 consecutive u32 (8 channels)
        uint32_t d[4];
#pragma unroll
        for (int j = 0; j < 4; ++j) {
            uint32_t a = lds[w * 67 + (cp4 * 4 + j) * 2];
            uint32_t b = lds[w * 67 + (cp4 * 4 + j) * 2 + 1];
            d[j] = arr ? ((a >> 16) | (b & 0xffff0000u))
                       : ((a & 0xffffu) | (b << 16));
        }
        int o = (((n * H_ + h) * 2 + (cp4 >> 2)) * W_ + w) * 16 + (cp4 & 3) * 4;
        uint32_t* dst = arr ? xt_lo : xt_hi;
        uint4 val; val.x = d[0]; val.y = d[1]; val.z = d[2]; val.w = d[3];
        *reinterpret_cast<uint4*>(&dst[o]) = val;
    }
}

// ---------------- Pass 2: w (OIHW f32) -> wt_hi/wt_lo [tap][k][c] f16 -------
__global__ __launch_bounds__(256)
void xform_w(const float* __restrict__ wgt, uint16_t* __restrict__ wt_hi,
             uint16_t* __restrict__ wt_lo) {
    int e = blockIdx.x * 256 + threadIdx.x;   // grid 144 -> e < 36864
    int t = e >> 12;
    int rem = e & 4095;
    int k = rem >> 6;
    int c = rem & 63;
    float v = wgt[(k * C_ + c) * 9 + t];
    f16 h = (f16)v;
    f16 l = (f16)(v - (float)h);
    wt_hi[e] = __builtin_bit_cast(uint16_t, h);
    wt_lo[e] = __builtin_bit_cast(uint16_t, l);
}

// ---------------- Pass 3: MFMA conv ----------------------------------------
// Block: (n, hq) -> output rows h0=4*hq .. h0+3. 256 thr = 4 waves.
// Wave wv = output row mr. Wave tile: 112 pix x 64 kout (nf = 0..3).
// LDS: 6 input rows x 114 pix x 64B, XOR-swizzled slots within each pixel:
//   LDS slot s' of pixel p holds channel-chunk  ch = s' ^ ((p>>1)&3).
#define EP_PITCH 116   // epilogue restage pitch (dwords): 16B-aligned, ~2-way banks
__global__ __launch_bounds__(256, 2)
void conv_mfma(const f16* __restrict__ xt_hi, const f16* __restrict__ xt_lo,
               const f16* __restrict__ wt_hi, const f16* __restrict__ wt_lo,
               float* __restrict__ out) {
    __shared__ alignas(16) char xs[6 * 114 * 64];   // 43,776 B (>= 4*16*116*4 too)

    const int tid = threadIdx.x;
    const int lane = tid & 63;
    const int wv = tid >> 6;
    const int mr = wv;            // output row within block
    const int l15 = lane & 15;
    const int l4 = lane >> 4;

    // XCD-chunked swizzle: grid 896 = 8 XCDs x 112 contiguous blocks each.
    const int bid = (blockIdx.x & 7) * 112 + (blockIdx.x >> 3);
    const int n = bid / 28;
    const int h0 = (bid % 28) * 4;

    // per-thread swizzled A-read byte offsets (pixel-within-row + slot), s=0..2:
    //   addr = (mr+r)*114*64 + f*1024 + sOff[s]
    int sOff[3];
#pragma unroll
    for (int s = 0; s < 3; ++s)
        sOff[s] = (l15 + s) * 64 + ((l4 ^ (((l15 + s) >> 1) & 3)) << 4);

    // per-lane pre-swizzled global source offset for DMA staging:
    // lane q writes LDS pixel p=1+i*16+(q>>2), slot q&3; content must be
    // chunk (q&3) ^ ((p>>1)&3) = (q&3) ^ ((((q>>2)+1)>>1)&3).
    const int slot_l = (lane & 3) ^ ((((lane >> 2) + 1) >> 1) & 3);
    const int src_off = (lane >> 2) * 64 + slot_l * 16;

    // ---- one-time halo zero: pixels 0,113 for all 6 rows; OOB rows fully
    {
        const f16x8 z = {};
        if (tid < 48) {           // 6 rows x 2 cols x 4 slots
            int r = tid / 8, pc = (tid >> 2) & 1, ch = tid & 3;
            int p = pc ? 113 : 0;
            *reinterpret_cast<f16x8*>(&xs[(r * 114 + p) * 64 + ch * 16]) = z;
        }
        if (h0 == 0)              // row r=0 (ih=-1)
            for (int q = tid; q < 114 * 4; q += 256)
                *reinterpret_cast<f16x8*>(&xs[(q >> 2) * 64 + (q & 3) * 16]) = z;
        if (h0 == H_ - 4)         // row r=5 (ih=112)
            for (int q = tid; q < 114 * 4; q += 256)
                *reinterpret_cast<f16x8*>(&xs[(5 * 114 + (q >> 2)) * 64 + (q & 3) * 16]) = z;
    }

    f32x4 acc[7][4];
#pragma unroll
    for (int f = 0; f < 7; ++f)
#pragma unroll
        for (int g = 0; g < 4; ++g) {
            f32x4 zz = {0.f, 0.f, 0.f, 0.f};
            acc[f][g] = zz;
        }

#pragma unroll
    for (int pp = 0; pp < 2; ++pp) {
        const f16* xp = pp ? xt_lo : xt_hi;
#pragma unroll
        for (int cs = 0; cs < 2; ++cs) {
            __syncthreads();   // previous phase done reading xs
            // stage 6 rows x 7 chunks = 42 DMA units, round-robin over waves
            for (int u = wv; u < 42; u += 4) {
                const int rr = u / 7;
                const int i = u - rr * 7;
                const int ih = h0 - 1 + rr;
                if ((unsigned)ih < (unsigned)H_) {
                    const char* gsrc = (const char*)xp +
                        (size_t)(((n * H_ + ih) * 2 + cs) * W_) * 64 +
                        i * 1024 + src_off;
                    __builtin_amdgcn_global_load_lds(
                        (g_u32*)gsrc,
                        (l_u32*)(&xs[(rr * 114 + 1) * 64 + i * 1024]), 16, 0, 0);
                }
            }
            __syncthreads();   // staging visible

            const int c0 = cs * 32;
#pragma unroll
            for (int tap = 0; tap < 9; ++tap) {
                const int r = tap / 3;
                const int s = tap % 3;
                // B frags: lane holds wt[tap][kout = nf*16 + l15][c0 + l4*8..+7]
                const int wo = (tap * K_ + l15) * C_ + c0 + l4 * 8;
                f16x8 Bh[4], Bl[4];
#pragma unroll
                for (int nf = 0; nf < 4; ++nf) {
                    Bh[nf] = *reinterpret_cast<const f16x8*>(&wt_hi[wo + nf * 16 * C_]);
                    if (pp == 0)
                        Bl[nf] = *reinterpret_cast<const f16x8*>(&wt_lo[wo + nf * 16 * C_]);
                }
                const int rb = (mr + r) * 114 * 64;
#pragma unroll
                for (int f = 0; f < 7; ++f) {
                    const f16x8 A = *reinterpret_cast<const f16x8*>(
                        &xs[rb + f * 1024 + sOff[s]]);
#pragma unroll
                    for (int nf = 0; nf < 4; ++nf) {
                        acc[f][nf] = __builtin_amdgcn_mfma_f32_16x16x32_f16(
                            A, Bh[nf], acc[f][nf], 0, 0, 0);
                        if (pp == 0)
                            acc[f][nf] = __builtin_amdgcn_mfma_f32_16x16x32_f16(
                                A, Bl[nf], acc[f][nf], 0, 0, 0);
                    }
                }
            }
        }
    }

    // ---- epilogue: restage through LDS for 448B-contiguous global writes.
    // Wave-private region: eps + wv*16*EP_PITCH dwords (16 k-rows x 112 w).
    __syncthreads();   // all compute reads of xs done; safe to reuse
    float* myep = reinterpret_cast<float*>(xs) + wv * 16 * EP_PITCH;
    const int h = h0 + mr;
#pragma unroll
    for (int nf = 0; nf < 4; ++nf) {
        // scatter D-frags: lane -> k-row l15, cols f*16 + l4*4 .. +3
#pragma unroll
        for (int f = 0; f < 7; ++f)
            *reinterpret_cast<f32x4*>(&myep[l15 * EP_PITCH + f * 16 + l4 * 4]) =
                acc[f][nf];
        // stream out: 16 rows x 28 float4 = 448 units, 7 iters of 64 lanes.
        // (wave-private region: same-wave LDS ordering; lgkmcnt by compiler)
#pragma unroll
        for (int i = 0; i < 7; ++i) {
            int flat = i * 64 + lane;        // 0..447
            int rr = flat / 28;              // k row 0..15
            int c4 = flat - rr * 28;         // float4 col 0..27
            const f32x4 val =
                *reinterpret_cast<const f32x4*>(&myep[rr * EP_PITCH + c4 * 4]);
            *reinterpret_cast<f32x4*>(
                &out[((n * K_ + nf * 16 + rr) * H_ + h) * W_ + c4 * 4]) = val;
        }
    }
}

// ---------------- Fallback: fp32 direct (v1) -------------------------------
constexpr int CB = 8;
constexpr int WP = 114;
__global__ __launch_bounds__(256, 4)
void conv3x3_fp32_v1(const float* __restrict__ x, const float* __restrict__ wgt,
                     float* __restrict__ out) {
    __shared__ float xsf[CB][3][WP];
    __shared__ float wsf[CB][9][K_];
    const int tid = threadIdx.x;
    const int tw = tid & 15, tk = tid >> 4;
    const int w0 = tw * 7, k0 = tk * 4;
    const int h = blockIdx.x % H_;
    const int n = blockIdx.x / H_;
    float acc[4][7];
#pragma unroll
    for (int a = 0; a < 4; ++a)
#pragma unroll
        for (int b = 0; b < 7; ++b) acc[a][b] = 0.f;
    for (int c0 = 0; c0 < C_; c0 += CB) {
        __syncthreads();
        for (int idx = tid; idx < CB * 3 * WP; idx += 256) {
            int cc = idx / (3 * WP);
            int rem = idx - cc * (3 * WP);
            int r = rem / WP, j = rem - r * WP;
            int ih = h - 1 + r, iw = j - 1;
            float v = 0.f;
            if ((unsigned)ih < (unsigned)H_ && (unsigned)iw < (unsigned)W_)
                v = x[((n * C_ + c0 + cc) * H_ + ih) * W_ + iw];
            xsf[cc][r][j] = v;
        }
        for (int idx = tid; idx < CB * 9 * K_; idx += 256) {
            int k = idx & 63, t = idx >> 6;
            int p = t % 9, cc = t / 9;
            wsf[cc][p][k] = wgt[(k * C_ + cc + c0) * 9 + p];
        }
        __syncthreads();
#pragma unroll
        for (int cc = 0; cc < CB; ++cc)
#pragma unroll
            for (int kh = 0; kh < 3; ++kh) {
                float xv[9];
#pragma unroll
                for (int i = 0; i < 9; ++i) xv[i] = xsf[cc][kh][w0 + i];
#pragma unroll
                for (int kw = 0; kw < 3; ++kw) {
                    const float4 wvv4 = *reinterpret_cast<const float4*>(&wsf[cc][kh * 3 + kw][k0]);
                    const float wvv[4] = {wvv4.x, wvv4.y, wvv4.z, wvv4.w};
#pragma unroll
                    for (int kk = 0; kk < 4; ++kk)
#pragma unroll
                        for (int wi = 0; wi < 7; ++wi)
                            acc[kk][wi] = fmaf(wvv[kk], xv[wi + kw], acc[kk][wi]);
                }
            }
    }
#pragma unroll
    for (int kk = 0; kk < 4; ++kk) {
        float* op = &out[((n * K_ + k0 + kk) * H_ + h) * W_ + w0];
#pragma unroll
        for (int wi = 0; wi < 7; ++wi) op[wi] = acc[kk][wi];
    }
}

extern "C" void kernel_launch(void* const* d_in, const int* in_sizes, int n_in,
                              void* d_out, int out_size, void* d_ws, size_t ws_size,
                              hipStream_t stream) {
    const float* x = (const float*)d_in[0];
    const float* wgt = (const float*)d_in[1];
    float* out = (float*)d_out;

    if (ws_size < WS_NEED) {
        hipLaunchKernelGGL(conv3x3_fp32_v1, dim3(N_ * H_), dim3(256), 0, stream,
                           x, wgt, out);
        return;
    }

    char* ws = (char*)d_ws;
    f16* xt_hi = (f16*)ws;
    f16* xt_lo = xt_hi + XT_E;
    f16* wt_hi = xt_lo + XT_E;
    f16* wt_lo = wt_hi + WT_E;

    hipLaunchKernelGGL(xform_x, dim3(N_ * H_), dim3(256), 0, stream,
                       x, (uint32_t*)xt_hi, (uint32_t*)xt_lo);
    hipLaunchKernelGGL(xform_w, dim3((int)(WT_E / 256)), dim3(256), 0, stream,
                       wgt, (uint16_t*)wt_hi, (uint16_t*)wt_lo);
    hipLaunchKernelGGL(conv_mfma, dim3(N_ * 28), dim3(256), 0, stream,
                       xt_hi, xt_lo, wt_hi, wt_lo, out);
}

// Round 9
// 266.401 us; speedup vs baseline: 1.3497x; 1.2691x over previous
//
#include <hip/hip_runtime.h>
#include <stdint.h>

// Conv2d 3x3 SAME stride-1. x:(32,64,112,112) f32 NCHW, w:(64,64,3,3) OIHW.
// v9: single-f16 MFMA implicit conv (dropped hi/lo split: harness tol 0.5 abs,
//     f16 conv error ~0.1 max -> passes; MFMA work /3, xt bytes /2).
// vs v8 (conv 161us MfmaUtil 22% WRITE 174MB; xform_x ~150us):
//   - 2 phases (cs chunks) instead of 4; single B-frag set.
//   - block-level epilogue: scatter to ep[16k][4h][116] in LDS, stream whole
//     (k, 4row) 1792B slabs = 14 aligned lines -> write amp ~1.0.
//   - xform_x single-plane rewrite: u16 LDS pitch 70, uint4 stores, ~154MB.
//   - kept: XOR slot swizzle (conflicts 3.6M->344K in v8), DMA staging,
//     XCD-chunked block swizzle.

#define N_ 32
#define C_ 64
#define H_ 112
#define W_ 112
#define K_ 64

typedef _Float16 f16;
typedef _Float16 f16x8 __attribute__((ext_vector_type(8)));
typedef float f32x4 __attribute__((ext_vector_type(4)));

typedef __attribute__((address_space(1))) const uint32_t g_u32;
typedef __attribute__((address_space(3))) uint32_t l_u32;

static constexpr size_t XT_E = (size_t)N_ * H_ * W_ * C_;  // f16 elems
static constexpr size_t WT_E = (size_t)9 * K_ * C_;
static constexpr size_t WS_NEED = (XT_E + WT_E) * 2;       // bytes

// ---------------- Pass 1: x (NCHW f32) -> xt f16 [n][h][cs=2][w][32c] -------
__global__ __launch_bounds__(256)
void xform_x(const float* __restrict__ x, uint32_t* __restrict__ xt) {
    __shared__ uint16_t sx[112 * 70];   // [w][c] pitch 70 (bank-spread, u32-even)
    const int tid = threadIdx.x;
    const int n = blockIdx.x / H_;
    const int h = blockIdx.x % H_;

    // load: 1792 float4 units: c = q/28, wq = (q%28)*4
#pragma unroll
    for (int k = 0; k < 7; ++k) {
        int q = tid + k * 256;
        int c = q / 28;
        int wq = (q % 28) * 4;
        const float4 v = *reinterpret_cast<const float4*>(
            &x[((n * C_ + c) * H_ + h) * W_ + wq]);
        sx[(wq + 0) * 70 + c] = __builtin_bit_cast(uint16_t, (f16)v.x);
        sx[(wq + 1) * 70 + c] = __builtin_bit_cast(uint16_t, (f16)v.y);
        sx[(wq + 2) * 70 + c] = __builtin_bit_cast(uint16_t, (f16)v.z);
        sx[(wq + 3) * 70 + c] = __builtin_bit_cast(uint16_t, (f16)v.w);
    }
    __syncthreads();
    // store: 896 uint4 units: w = u>>3, cp8 = u&7 (8 channels = 4 u32)
#pragma unroll
    for (int i = 0; i < 4; ++i) {
        int u = tid + i * 256;
        if (u < 896) {
            int w = u >> 3;
            int cp8 = u & 7;
            const uint32_t* row =
                reinterpret_cast<const uint32_t*>(&sx[w * 70 + cp8 * 8]);
            uint4 val;
            val.x = row[0]; val.y = row[1]; val.z = row[2]; val.w = row[3];
            int o = (((n * H_ + h) * 2 + (cp8 >> 2)) * W_ + w) * 16 +
                    (cp8 & 3) * 4;
            *reinterpret_cast<uint4*>(&xt[o]) = val;
        }
    }
}

// ---------------- Pass 2: w (OIHW f32) -> wt [tap][k][c] f16 ----------------
__global__ __launch_bounds__(256)
void xform_w(const float* __restrict__ wgt, uint16_t* __restrict__ wt) {
    int e = blockIdx.x * 256 + threadIdx.x;   // grid 144 -> e < 36864
    int t = e >> 12;
    int rem = e & 4095;
    int k = rem >> 6;
    int c = rem & 63;
    wt[e] = __builtin_bit_cast(uint16_t, (f16)wgt[(k * C_ + c) * 9 + t]);
}

// ---------------- Pass 3: MFMA conv ----------------------------------------
// Block: (n, hq) -> output rows h0=4*hq..h0+3. 4 waves, wave wv = row mr.
// Wave tile: 112 pix x 64 kout. LDS: 6 rows x 114 pix x 64B, XOR slot swizzle
//   slot' = ch ^ ((pix>>1)&3). Epilogue: block-shared ep[16][4][116] f32.
#define EP_K 464    // k-stride in floats (= 4*116)
#define EP_H 116    // h-stride in floats
__global__ __launch_bounds__(256, 3)
void conv_mfma(const f16* __restrict__ xt, const f16* __restrict__ wt,
               float* __restrict__ out) {
    __shared__ alignas(16) char xs[6 * 114 * 64];   // 43,776 B (ep needs 29,696)

    const int tid = threadIdx.x;
    const int lane = tid & 63;
    const int wv = tid >> 6;
    const int mr = wv;
    const int l15 = lane & 15;
    const int l4 = lane >> 4;

    // XCD-chunked swizzle: grid 896 = 8 XCDs x 112 contiguous blocks.
    const int bid = (blockIdx.x & 7) * 112 + (blockIdx.x >> 3);
    const int n = bid / 28;
    const int h0 = (bid % 28) * 4;

    // swizzled A-read offsets: addr = (mr+r)*7296 + f*1024 + sOff[s]
    int sOff[3];
#pragma unroll
    for (int s = 0; s < 3; ++s)
        sOff[s] = (l15 + s) * 64 + ((l4 ^ (((l15 + s) >> 1) & 3)) << 4);

    // pre-swizzled DMA source offset (lane q -> LDS pixel 1+i*16+(q>>2), slot q&3)
    const int slot_l = (lane & 3) ^ ((((lane >> 2) + 1) >> 1) & 3);
    const int src_off = (lane >> 2) * 64 + slot_l * 16;

    // one-time halo zero: pixels 0,113 all 6 rows; OOB rows fully
    {
        const f16x8 z = {};
        if (tid < 48) {
            int r = tid / 8, pc = (tid >> 2) & 1, ch = tid & 3;
            int p = pc ? 113 : 0;
            *reinterpret_cast<f16x8*>(&xs[(r * 114 + p) * 64 + ch * 16]) = z;
        }
        if (h0 == 0)
            for (int q = tid; q < 114 * 4; q += 256)
                *reinterpret_cast<f16x8*>(&xs[(q >> 2) * 64 + (q & 3) * 16]) = z;
        if (h0 == H_ - 4)
            for (int q = tid; q < 114 * 4; q += 256)
                *reinterpret_cast<f16x8*>(&xs[(5 * 114 + (q >> 2)) * 64 + (q & 3) * 16]) = z;
    }

    f32x4 acc[7][4];
#pragma unroll
    for (int f = 0; f < 7; ++f)
#pragma unroll
        for (int g = 0; g < 4; ++g) {
            f32x4 zz = {0.f, 0.f, 0.f, 0.f};
            acc[f][g] = zz;
        }

#pragma unroll
    for (int cs = 0; cs < 2; ++cs) {
        __syncthreads();   // previous phase done reading xs
        // stage 6 rows x 7 chunks = 42 DMA units over 4 waves
        for (int u = wv; u < 42; u += 4) {
            const int rr = u / 7;
            const int i = u - rr * 7;
            const int ih = h0 - 1 + rr;
            if ((unsigned)ih < (unsigned)H_) {
                const char* gsrc = (const char*)xt +
                    (size_t)(((n * H_ + ih) * 2 + cs) * W_) * 64 +
                    i * 1024 + src_off;
                __builtin_amdgcn_global_load_lds(
                    (g_u32*)gsrc,
                    (l_u32*)(&xs[(rr * 114 + 1) * 64 + i * 1024]), 16, 0, 0);
            }
        }
        __syncthreads();   // staging visible

        const int c0 = cs * 32;
#pragma unroll
        for (int tap = 0; tap < 9; ++tap) {
            const int r = tap / 3;
            const int s = tap % 3;
            // B frags: lane holds wt[tap][kout = nf*16 + l15][c0 + l4*8..+7]
            const int wo = (tap * K_ + l15) * C_ + c0 + l4 * 8;
            f16x8 B[4];
#pragma unroll
            for (int nf = 0; nf < 4; ++nf)
                B[nf] = *reinterpret_cast<const f16x8*>(&wt[wo + nf * 16 * C_]);
            const int rb = (mr + r) * 114 * 64;
#pragma unroll
            for (int f = 0; f < 7; ++f) {
                const f16x8 A = *reinterpret_cast<const f16x8*>(
                    &xs[rb + f * 1024 + sOff[s]]);
#pragma unroll
                for (int nf = 0; nf < 4; ++nf)
                    acc[f][nf] = __builtin_amdgcn_mfma_f32_16x16x32_f16(
                        A, B[nf], acc[f][nf], 0, 0, 0);
            }
        }
    }

    // ---- epilogue: block-level restage; stream (k, 4row) 1792B slabs.
    float* ep = reinterpret_cast<float*>(xs);
#pragma unroll
    for (int nf = 0; nf < 4; ++nf) {
        __syncthreads();   // prior reads of xs/ep done
        // scatter: lane -> k=l15, h=mr, w = f*16 + l4*4 (+j)
#pragma unroll
        for (int f = 0; f < 7; ++f)
            *reinterpret_cast<f32x4*>(
                &ep[l15 * EP_K + mr * EP_H + f * 16 + l4 * 4]) = acc[f][nf];
        __syncthreads();   // scatter visible to whole block
        // stream: 1792 f32x4 units = 16 k-slabs x 112 units (h-major within slab)
#pragma unroll
        for (int i = 0; i < 7; ++i) {
            int u = tid + i * 256;
            int k = u / 112;
            int idx = u - k * 112;
            int hl = idx / 28;
            int w4 = idx - hl * 28;
            const f32x4 val = *reinterpret_cast<const f32x4*>(
                &ep[k * EP_K + hl * EP_H + w4 * 4]);
            *reinterpret_cast<f32x4*>(
                &out[((n * K_ + nf * 16 + k) * H_ + h0 + hl) * W_ + w4 * 4]) = val;
        }
    }
}

// ---------------- Fallback: fp32 direct ------------------------------------
constexpr int CB = 8;
constexpr int WP = 114;
__global__ __launch_bounds__(256, 4)
void conv3x3_fp32_v1(const float* __restrict__ x, const float* __restrict__ wgt,
                     float* __restrict__ out) {
    __shared__ float xsf[CB][3][WP];
    __shared__ float wsf[CB][9][K_];
    const int tid = threadIdx.x;
    const int tw = tid & 15, tk = tid >> 4;
    const int w0 = tw * 7, k0 = tk * 4;
    const int h = blockIdx.x % H_;
    const int n = blockIdx.x / H_;
    float acc[4][7];
#pragma unroll
    for (int a = 0; a < 4; ++a)
#pragma unroll
        for (int b = 0; b < 7; ++b) acc[a][b] = 0.f;
    for (int c0 = 0; c0 < C_; c0 += CB) {
        __syncthreads();
        for (int idx = tid; idx < CB * 3 * WP; idx += 256) {
            int cc = idx / (3 * WP);
            int rem = idx - cc * (3 * WP);
            int r = rem / WP, j = rem - r * WP;
            int ih = h - 1 + r, iw = j - 1;
            float v = 0.f;
            if ((unsigned)ih < (unsigned)H_ && (unsigned)iw < (unsigned)W_)
                v = x[((n * C_ + c0 + cc) * H_ + ih) * W_ + iw];
            xsf[cc][r][j] = v;
        }
        for (int idx = tid; idx < CB * 9 * K_; idx += 256) {
            int k = idx & 63, t = idx >> 6;
            int p = t % 9, cc = t / 9;
            wsf[cc][p][k] = wgt[(k * C_ + cc + c0) * 9 + p];
        }
        __syncthreads();
#pragma unroll
        for (int cc = 0; cc < CB; ++cc)
#pragma unroll
            for (int kh = 0; kh < 3; ++kh) {
                float xv[9];
#pragma unroll
                for (int i = 0; i < 9; ++i) xv[i] = xsf[cc][kh][w0 + i];
#pragma unroll
                for (int kw = 0; kw < 3; ++kw) {
                    const float4 wvv4 = *reinterpret_cast<const float4*>(&wsf[cc][kh * 3 + kw][k0]);
                    const float wvv[4] = {wvv4.x, wvv4.y, wvv4.z, wvv4.w};
#pragma unroll
                    for (int kk = 0; kk < 4; ++kk)
#pragma unroll
                        for (int wi = 0; wi < 7; ++wi)
                            acc[kk][wi] = fmaf(wvv[kk], xv[wi + kw], acc[kk][wi]);
                }
            }
    }
#pragma unroll
    for (int kk = 0; kk < 4; ++kk) {
        float* op = &out[((n * K_ + k0 + kk) * H_ + h) * W_ + w0];
#pragma unroll
        for (int wi = 0; wi < 7; ++wi) op[wi] = acc[kk][wi];
    }
}

extern "C" void kernel_launch(void* const* d_in, const int* in_sizes, int n_in,
                              void* d_out, int out_size, void* d_ws, size_t ws_size,
                              hipStream_t stream) {
    const float* x = (const float*)d_in[0];
    const float* wgt = (const float*)d_in[1];
    float* out = (float*)d_out;

    if (ws_size < WS_NEED) {
        hipLaunchKernelGGL(conv3x3_fp32_v1, dim3(N_ * H_), dim3(256), 0, stream,
                           x, wgt, out);
        return;
    }

    char* ws = (char*)d_ws;
    f16* xt = (f16*)ws;
    f16* wt = xt + XT_E;

    hipLaunchKernelGGL(xform_x, dim3(N_ * H_), dim3(256), 0, stream,
                       x, (uint32_t*)xt);
    hipLaunchKernelGGL(xform_w, dim3((int)(WT_E / 256)), dim3(256), 0, stream,
                       wgt, (uint16_t*)wt);
    hipLaunchKernelGGL(conv_mfma, dim3(N_ * 28), dim3(256), 0, stream,
                       xt, wt, out);
}